// Round 19
// baseline (602.251 us; speedup 1.0000x reference)
//
#include <hip/hip_runtime.h>
#include <hip/hip_bf16.h>

typedef __attribute__((ext_vector_type(8))) short short8v;
typedef __attribute__((ext_vector_type(4))) short short4v;
typedef __attribute__((ext_vector_type(4))) float f32x4;

constexpr int B_ = 2, S_ = 2048, H_ = 16, MM_ = 40;
constexpr int L_ = S_ + MM_;    // 2088
constexpr int LP_ = 2112;       // 33 * 64 padded kv length
constexpr int NT_ = 33;         // l tiles of 64
constexpr float QSCALE = 0.18033688011112042f;   // 0.125/ln2 folded into Q proj

struct S2 { short hi, lo; };
__device__ __forceinline__ S2 split2(float f) {
    unsigned u = __builtin_bit_cast(unsigned, f);
    short hi = (short)(u >> 16);
    float fh = __builtin_bit_cast(float, u & 0xFFFF0000u);
    float fl = f - fh;                       // exact
    short lo = (short)(__builtin_bit_cast(unsigned, fl) >> 16);
    return {hi, lo};
}
__device__ __forceinline__ short f2bh(float f) {
    unsigned u = __builtin_bit_cast(unsigned, f);
    u = (u + 0x7FFFu + ((u >> 16) & 1u)) >> 16;
    return (short)u;
}
__device__ __forceinline__ f32x4 mfma16(short8v a, short8v b, f32x4 c) {
    return __builtin_amdgcn_mfma_f32_16x16x32_bf16(a, b, c, 0, 0, 0);
}
__device__ __forceinline__ unsigned cvt_pk_bf16(float a, float b) {
    unsigned r;
    asm("v_cvt_pk_bf16_f32 %0, %1, %2" : "=v"(r) : "v"(a), "v"(b));
    return r;
}

// ---------------------------------------------------------------------------
// Weight split+transpose (batched z=6): W[k][n] -> WTh/WTl[n][k] bf16 hi/lo.
// ---------------------------------------------------------------------------
__global__ __launch_bounds__(256) void wsplit6_kernel(
    const float* __restrict__ W0, const float* __restrict__ W1,
    const float* __restrict__ W2, const float* __restrict__ W3,
    const float* __restrict__ W4, const float* __restrict__ W5,
    short* __restrict__ WT)
{
    const float* Ws[6] = {W0, W1, W2, W3, W4, W5};
    const float* W = Ws[blockIdx.z];
    short* WTh = WT + (size_t)blockIdx.z * 2097152;
    short* WTl = WTh + 1048576;
    __shared__ float T[64][68];
    const int t = threadIdx.x;
    const int k0 = blockIdx.x * 64, n0 = blockIdx.y * 64;
    {
        int r = t >> 2, c = (t & 3) * 16;
        const float* src = W + (size_t)(k0 + r) * 1024 + n0 + c;
        *(float4*)&T[r][c + 0]  = *(const float4*)(src + 0);
        *(float4*)&T[r][c + 4]  = *(const float4*)(src + 4);
        *(float4*)&T[r][c + 8]  = *(const float4*)(src + 8);
        *(float4*)&T[r][c + 12] = *(const float4*)(src + 12);
    }
    __syncthreads();
    {
        int n = t >> 2, ks = (t & 3) * 16;
        short8v h0, h1, l0, l1;
#pragma unroll
        for (int j = 0; j < 8; ++j) {
            S2 a = split2(T[ks + j][n]);     h0[j] = a.hi; l0[j] = a.lo;
            S2 b = split2(T[ks + 8 + j][n]); h1[j] = b.hi; l1[j] = b.lo;
        }
        size_t dst = (size_t)(n0 + n) * 1024 + k0 + ks;
        *(short8v*)(WTh + dst) = h0;  *(short8v*)(WTh + dst + 8) = h1;
        *(short8v*)(WTl + dst) = l0;  *(short8v*)(WTl + dst + 8) = l1;
    }
}

// ---------------------------------------------------------------------------
// GEMM device core: 128x128 tile, BK=32, split-bf16 3-term MFMA.
// ---------------------------------------------------------------------------
template<int ASRC>
__device__ __forceinline__ void gemm_core(
    const float* __restrict__ Af, const short* __restrict__ Ahg,
    const short* __restrict__ Alg, const short* __restrict__ WTh,
    const short* __restrict__ WTl, const float* __restrict__ bias,
    float bscale, float scale,
    short* __restrict__ Oh, short* __restrict__ Ol, float* __restrict__ Of,
    int M, int RPB, int TD, int loff, int omode, int bx, int by,
    int kbeg, int kend)
{
    __shared__ short Ah[128][40];
    __shared__ short Al[128][40];
    __shared__ short Bh[128][40];
    __shared__ short Bl[128][40];
    const int tid = threadIdx.x;
    const int lane = tid & 63, wid = tid >> 6;
    const int wr = wid >> 1, wc = wid & 1;
    const int row0 = by * 128, col0 = bx * 128;
    const int sr = tid >> 1, sc = (tid & 1) << 4;

    f32x4 acc[4][4] = {};

    for (int k0 = kbeg; k0 < kend; k0 += 32) {
        if (ASRC == 0) {
            float f[16];
            int gr = row0 + sr;
            if (gr < M) {
                const float* ap = Af + (size_t)gr * 1024 + k0 + sc;
                float4 a0 = *(const float4*)(ap + 0);
                float4 a1 = *(const float4*)(ap + 4);
                float4 a2 = *(const float4*)(ap + 8);
                float4 a3 = *(const float4*)(ap + 12);
                f[0]=a0.x; f[1]=a0.y; f[2]=a0.z; f[3]=a0.w;
                f[4]=a1.x; f[5]=a1.y; f[6]=a1.z; f[7]=a1.w;
                f[8]=a2.x; f[9]=a2.y; f[10]=a2.z; f[11]=a2.w;
                f[12]=a3.x; f[13]=a3.y; f[14]=a3.z; f[15]=a3.w;
            } else {
#pragma unroll
                for (int j = 0; j < 16; ++j) f[j] = 0.f;
            }
            short8v h0, h1, l0, l1;
#pragma unroll
            for (int j = 0; j < 8; ++j) {
                S2 s = split2(f[j]); h0[j] = s.hi; l0[j] = s.lo;
            }
#pragma unroll
            for (int j = 0; j < 8; ++j) {
                S2 s = split2(f[8 + j]); h1[j] = s.hi; l1[j] = s.lo;
            }
            *(short8v*)&Ah[sr][sc] = h0; *(short8v*)&Ah[sr][sc + 8] = h1;
            *(short8v*)&Al[sr][sc] = l0; *(short8v*)&Al[sr][sc + 8] = l1;
        } else {
            const short* ah = Ahg + (size_t)(row0 + sr) * 1024 + k0 + sc;
            const short* al = Alg + (size_t)(row0 + sr) * 1024 + k0 + sc;
            *(short8v*)&Ah[sr][sc]     = *(const short8v*)ah;
            *(short8v*)&Ah[sr][sc + 8] = *(const short8v*)(ah + 8);
            *(short8v*)&Al[sr][sc]     = *(const short8v*)al;
            *(short8v*)&Al[sr][sc + 8] = *(const short8v*)(al + 8);
        }
        {
            const short* bh = WTh + (size_t)(col0 + sr) * 1024 + k0 + sc;
            const short* bl = WTl + (size_t)(col0 + sr) * 1024 + k0 + sc;
            *(short8v*)&Bh[sr][sc]     = *(const short8v*)bh;
            *(short8v*)&Bh[sr][sc + 8] = *(const short8v*)(bh + 8);
            *(short8v*)&Bl[sr][sc]     = *(const short8v*)bl;
            *(short8v*)&Bl[sr][sc + 8] = *(const short8v*)(bl + 8);
        }
        __syncthreads();
        const int kof = (lane >> 4) << 3;
        const int ar = lane & 15;
        short8v afh[4], afl[4], bfh[4], bfl[4];
#pragma unroll
        for (int i = 0; i < 4; ++i) {
            afh[i] = *(const short8v*)&Ah[wr * 64 + i * 16 + ar][kof];
            afl[i] = *(const short8v*)&Al[wr * 64 + i * 16 + ar][kof];
            bfh[i] = *(const short8v*)&Bh[wc * 64 + i * 16 + ar][kof];
            bfl[i] = *(const short8v*)&Bl[wc * 64 + i * 16 + ar][kof];
        }
#pragma unroll
        for (int i = 0; i < 4; ++i)
#pragma unroll
            for (int j = 0; j < 4; ++j) {
                acc[i][j] = mfma16(afh[i], bfh[j], acc[i][j]);
                acc[i][j] = mfma16(afh[i], bfl[j], acc[i][j]);
                acc[i][j] = mfma16(afl[i], bfh[j], acc[i][j]);
            }
        __syncthreads();
    }

#pragma unroll
    for (int i = 0; i < 4; ++i) {
#pragma unroll
        for (int j = 0; j < 4; ++j) {
            int colb = col0 + wc * 64 + j * 16 + (lane & 15);
            float bv = bias[colb] * bscale;
            int rowb = row0 + wr * 64 + i * 16 + ((lane >> 4) << 2);
            if (omode == 2) {
                if (rowb < M) {
                    int bb = rowb / RPB, tt = rowb % RPB;
                    int hh = colb >> 6, dh = colb & 63;
                    short4v hs;
#pragma unroll
                    for (int r = 0; r < 4; ++r)
                        hs[r] = f2bh((acc[i][j][r] + bv) * scale);
                    size_t dst = ((size_t)(bb * H_ + hh) * 64 + dh) * LP_ + loff + tt;
                    *(short4v*)(Oh + dst) = hs;
                }
            } else {
#pragma unroll
                for (int r = 0; r < 4; ++r) {
                    int row = rowb + r;
                    if (row < M) {
                        float o = (acc[i][j][r] + bv) * scale;
                        int bb = row / RPB, tt = row % RPB;
                        if (omode == 0) {
                            Of[((size_t)bb * TD + loff + tt) * 1024 + colb] = o;
                        } else {
                            int hh = colb >> 6, dh = colb & 63;
                            size_t dst = ((size_t)(bb * H_ + hh) * TD + loff + tt) * 64 + dh;
                            S2 s = split2(o);
                            Oh[dst] = s.hi; Ol[dst] = s.lo;
                        }
                    }
                }
            }
        }
    }
}

// ---------------------------------------------------------------------------
// Mega projection kernel: z=0 = mask pack + V pad clear; z in {1,2,3} =
// Q/K/V big GEMMs; z in {4..7} = memory K/V GEMMs (by==0 only).
// ---------------------------------------------------------------------------
__global__ __launch_bounds__(256) void qkv_gemm(
    const float* __restrict__ q_in, const float* __restrict__ k_in,
    const float* __restrict__ v_in, const float* __restrict__ kmem,
    const float* __restrict__ vmem, const short* __restrict__ WT,
    const float* __restrict__ bq, const float* __restrict__ bk,
    const float* __restrict__ bv, const float* __restrict__ bkm,
    const float* __restrict__ bvm,
    short* __restrict__ Qh, short* __restrict__ Ql,
    short* __restrict__ Kh, short* __restrict__ Kl, short* __restrict__ Vh,
    const float* __restrict__ mask, unsigned* __restrict__ mp)
{
    const int z = blockIdx.z;
    if (z == 0) {
        const int blk = blockIdx.y * 8 + blockIdx.x;      // 0..255
        for (int rr = 0; rr < 16; ++rr) {
            const int row = blk * 16 + rr;
            const float* mr = mask + (size_t)row * L_;
            unsigned* orow = mp + (size_t)row * 68;
            for (int wd = threadIdx.x; wd < 66; wd += 256) {
                int l0 = wd * 32;
                unsigned bits = 0u;
                int lim = (wd < 65) ? 32 : 8;
                for (int j = 0; j < lim; j += 4) {
                    float4 m4 = *(const float4*)(mr + l0 + j);
                    bits |= ((unsigned)(m4.x != 0.f)) << (j + 0);
                    bits |= ((unsigned)(m4.y != 0.f)) << (j + 1);
                    bits |= ((unsigned)(m4.z != 0.f)) << (j + 2);
                    bits |= ((unsigned)(m4.w != 0.f)) << (j + 3);
                }
                if (wd == 65) bits |= 0xFFFFFF00u;
                orow[wd] = bits;
            }
        }
        for (int k = threadIdx.x; k < 192; k += 256) {
            int g = blk * 192 + k;
            int rd = g / 24, l = L_ + g % 24;
            Vh[(size_t)rd * LP_ + l] = 0;
        }
        return;
    }
    if (z >= 4) {
        if (blockIdx.y != 0) return;
        const int which = (z - 4) >> 1, b = (z - 4) & 1;   // which: 0=K, 1=V
        const float* A = which ? vmem : kmem;
        const short* WTh = WT + (size_t)(3 + which) * 2097152;
        const short* WTl = WTh + 1048576;
        const float* bias = which ? bvm : bkm;
        short* Oh = which ? (Vh + (size_t)b * H_ * 64 * LP_)
                          : (Kh + (size_t)b * H_ * LP_ * 64);
        short* Ol = which ? nullptr : (Kl + (size_t)b * H_ * LP_ * 64);
        gemm_core<0>(A, nullptr, nullptr, WTh, WTl, bias, 1.0f, 1.0f,
                     Oh, Ol, nullptr, 40, 40, LP_, S_, which ? 2 : 1,
                     blockIdx.x, 0, 0, 1024);
        return;
    }
    const int g = z - 1;                           // 0=Q 1=K 2=V
    const float* A = (g == 0) ? q_in : (g == 1) ? k_in : v_in;
    const short* WTh = WT + (size_t)g * 2097152;
    const short* WTl = WTh + 1048576;
    const float* bias = (g == 0) ? bq : (g == 1) ? bk : bv;
    float scale = (g == 0) ? QSCALE : 1.0f;
    short* Oh = (g == 0) ? Qh : (g == 1) ? Kh : Vh;
    short* Ol = (g == 0) ? Ql : Kl;
    int omode = (g == 2) ? 2 : 1;
    int TD = (g == 0) ? S_ : LP_;
    gemm_core<0>(A, nullptr, nullptr, WTh, WTl, bias, 1.0f, scale,
                 Oh, Ol, nullptr, 4096, 2048, TD, 0, omode,
                 blockIdx.x, blockIdx.y, 0, 1024);
}

// ---------------------------------------------------------------------------
// Out projection, split-K=2: z selects K half; writes fp32 partials.
// ---------------------------------------------------------------------------
__global__ __launch_bounds__(256) void out_gemm(
    const short* __restrict__ Ch, const short* __restrict__ Cl,
    const short* __restrict__ WT, const float* __restrict__ bo,
    float* __restrict__ Po0, float* __restrict__ Po1)
{
    const int z = blockIdx.z;
    const short* WTh = WT + (size_t)5 * 2097152;
    gemm_core<1>(nullptr, Ch, Cl, WTh, WTh + 1048576, bo,
                 z == 0 ? 1.0f : 0.0f, 1.0f,
                 nullptr, nullptr, z == 0 ? Po0 : Po1, 4096, 2048, S_, 0, 0,
                 blockIdx.x, blockIdx.y, z * 512, z * 512 + 512);
}

// ---------------------------------------------------------------------------
// Fused attention v12 (R18 best config): single-buffered K/V, 32.7 KB LDS,
// 4 blocks/CU, 1024 blocks x 4 waves, 64 q-rows/block. setprio hoisted to
// one toggle per MFMA region.
// ---------------------------------------------------------------------------
__global__ __launch_bounds__(256) void attn4_kernel(
    const short* __restrict__ Qh, const short* __restrict__ Ql,
    const short* __restrict__ Kh, const short* __restrict__ Kl,
    const short* __restrict__ Vh, const unsigned* __restrict__ mp,
    float* __restrict__ attn, float* __restrict__ invg,
    short* __restrict__ Ch, short* __restrict__ Cl)
{
    __shared__ short KhB[64][64];      // 8 KB
    __shared__ short KlB[64][64];      // 8 KB
    __shared__ short VB[64][64];       // 8 KB
    __shared__ short Ph[4][16][68];    // 8.5 KB

    const int id = blockIdx.x;
    const int wg = (id & 7) * 128 + (id >> 3);     // XCD swizzle (1024 = 8*128)
    const int bh = wg >> 5, qb = wg & 31;
    const int b = bh >> 4, h = bh & 15;
    const int lane = threadIdx.x & 63, w = threadIdx.x >> 6;
    const int lq = lane & 15, hi = lane >> 4;
    const int sw = lq & 7;
    const int q0 = qb * 64 + w * 16;
    const int q = q0 + lq;

    const char* kh_g = (const char*)(Kh + (size_t)bh * LP_ * 64);
    const char* kl_g = (const char*)(Kl + (size_t)bh * LP_ * 64);
    const char* v_g  = (const char*)(Vh + (size_t)bh * 64 * LP_);

    auto stage_k = [&](int tt) {
#pragma unroll
        for (int i = 0; i < 2; ++i) {
            int o = w * 2048 + i * 1024 + lane * 16;   // linear LDS byte offset
            int r = o >> 7, c = (o >> 4) & 7;
            int cs = c ^ (r & 7);                      // inverse-swizzled source
            const char* sh = kh_g + (size_t)tt * 8192 + r * 128 + cs * 16;
            const char* sl = kl_g + (size_t)tt * 8192 + r * 128 + cs * 16;
            __builtin_amdgcn_global_load_lds((const void*)sh,
                (void*)((char*)&KhB[0][0] + w * 2048 + i * 1024), 16, 0, 0);
            __builtin_amdgcn_global_load_lds((const void*)sl,
                (void*)((char*)&KlB[0][0] + w * 2048 + i * 1024), 16, 0, 0);
        }
    };
    auto stage_v = [&](int tt) {
#pragma unroll
        for (int i = 0; i < 2; ++i) {
            int o = w * 2048 + i * 1024 + lane * 16;
            int dh = o >> 7, c = (o >> 4) & 7;
            int cs = c ^ (dh & 7);
            const char* src = v_g + (size_t)dh * (LP_ * 2) + (size_t)tt * 128 + cs * 16;
            __builtin_amdgcn_global_load_lds((const void*)src,
                (void*)((char*)&VB[0][0] + w * 2048 + i * 1024), 16, 0, 0);
        }
    };

    const size_t qbase = ((size_t)bh * S_ + q) * 64 + hi * 8;
    const short8v qh0 = *(const short8v*)(Qh + qbase);
    const short8v qh1 = *(const short8v*)(Qh + qbase + 32);
    const short8v ql0 = *(const short8v*)(Ql + qbase);
    const short8v ql1 = *(const short8v*)(Ql + qbase + 32);
    const unsigned* mrow = mp + ((size_t)b * S_ + q) * 68;

    const int dr = lane >> 2, dc = lane & 3;
    short* dbase = (short*)(attn + ((size_t)bh * S_ + q0 + dr) * L_);

    float sm = 0.f;
    f32x4 pv[4] = {};

    stage_k(0);
    stage_v(0);
    __syncthreads();

    for (int t = 0; t < NT_; ++t) {
        const unsigned w0 = mrow[2 * t], w1 = mrow[2 * t + 1];
        const short8v* kp = (const short8v*)&KhB[0][0];
        const short8v* lp = (const short8v*)&KlB[0][0];
        // K frags for all 4 sub-steps
        short8v kh0s[4], kh1s[4], kl0s[4], kl1s[4];
#pragma unroll
        for (int ls = 0; ls < 4; ++ls) {
            const int r = ls * 16 + lq;
            kh0s[ls] = kp[r * 8 + (hi ^ sw)];
            kh1s[ls] = kp[r * 8 + ((hi + 4) ^ sw)];
            kl0s[ls] = lp[r * 8 + (hi ^ sw)];
            kl1s[ls] = lp[r * 8 + ((hi + 4) ^ sw)];
        }
        f32x4 accs[4];
        __builtin_amdgcn_s_setprio(1);
#pragma unroll
        for (int ls = 0; ls < 4; ++ls) {
            f32x4 acc = {0.f, 0.f, 0.f, 0.f};
            acc = mfma16(kh0s[ls], qh0, acc); acc = mfma16(kh1s[ls], qh1, acc);
            acc = mfma16(kh0s[ls], ql0, acc); acc = mfma16(kh1s[ls], ql1, acc);
            acc = mfma16(kl0s[ls], qh0, acc); acc = mfma16(kl1s[ls], qh1, acc);
            accs[ls] = acc;
        }
        __builtin_amdgcn_s_setprio(0);
#pragma unroll
        for (int ls = 0; ls < 4; ++ls) {
            const unsigned wb = (ls & 2) ? w1 : w0;
            const int sh = (ls & 1) * 16 + hi * 4;
            float pr[4];
#pragma unroll
            for (int r2 = 0; r2 < 4; ++r2) {
                float e = __builtin_exp2f(accs[ls][r2]);
                pr[r2] = ((wb >> (sh + r2)) & 1u) ? 0.f : e;
            }
            sm += (pr[0] + pr[1]) + (pr[2] + pr[3]);
            *(uint2*)&Ph[w][lq][ls * 16 + hi * 4] =
                uint2{cvt_pk_bf16(pr[0], pr[1]), cvt_pk_bf16(pr[2], pr[3])};
        }
        {   // dense packed-bf16 p~ store (from Ph)
            short8v v0 = *(const short8v*)&Ph[w][dr][dc * 8];
            short8v v1 = *(const short8v*)&Ph[w][dr][32 + dc * 8];
            short* dst = dbase + t * 64 + dc * 8;
            if (t < NT_ - 1) { *(short8v*)dst = v0; *(short8v*)(dst + 32) = v1; }
            else { *(short8v*)dst = v0; if (dc == 0) *(short8v*)(dst + 32) = v1; }
        }
        {   // PV
            const short8v pa0 = *(const short8v*)&Ph[w][lq][hi * 8];
            const short8v pa1 = *(const short8v*)&Ph[w][lq][32 + hi * 8];
            const short8v* vp = (const short8v*)&VB[0][0];
            __builtin_amdgcn_s_setprio(1);
#pragma unroll
            for (int j = 0; j < 4; ++j)
                pv[j] = mfma16(pa0, vp[(j * 16 + lq) * 8 + (hi ^ sw)], pv[j]);
#pragma unroll
            for (int j = 0; j < 4; ++j)
                pv[j] = mfma16(pa1, vp[(j * 16 + lq) * 8 + ((hi + 4) ^ sw)], pv[j]);
            __builtin_amdgcn_s_setprio(0);
        }
        if (t < NT_ - 1) {
            __syncthreads();            // all reads of the buffers done
            stage_k(t + 1);
            stage_v(t + 1);
            __syncthreads();            // staged data visible
        }
    }

    // row sums (lane l holds sum of row q0 + (l&15))
    sm += __shfl_xor(sm, 16);
    sm += __shfl_xor(sm, 32);
    if (lane < 16)
        invg[(size_t)bh * S_ + q0 + lane] = sm > 0.f ? 1.0f / sm : 0.f;

    // ctx write (normalized, split bf16)
#pragma unroll
    for (int r = 0; r < 4; ++r) {
        float sv = __shfl(sm, hi * 4 + r);
        float iv = sv > 0.f ? 1.0f / sv : 0.f;
#pragma unroll
        for (int j = 0; j < 4; ++j) {
            size_t dst = ((size_t)b * S_ + q0 + hi * 4 + r) * 1024 + h * 64 + j * 16 + lq;
            S2 sp = split2(pv[j][r] * iv);
            Ch[dst] = sp.hi; Cl[dst] = sp.lo;
        }
    }
}

// ---------------------------------------------------------------------------
// Fused BW tail (LDS-free): blocks 0..2047 = expand+normalize attn in place;
// blocks 2048..6143 = split-K partial sum into d_out. Both branches are
// pure-BW with zero LDS -> full occupancy for both.
// ---------------------------------------------------------------------------
__global__ __launch_bounds__(256) void norm_add(
    float* __restrict__ attn, const float* __restrict__ invg,
    const float* __restrict__ Po0, const float* __restrict__ Po1,
    float* __restrict__ outp)
{
    if (blockIdx.x >= 2048) {
        int i = ((blockIdx.x - 2048) * 256 + threadIdx.x) * 4;   // 4,194,304 floats
        float4 a = *(const float4*)(Po0 + i);
        float4 b = *(const float4*)(Po1 + i);
        a.x += b.x; a.y += b.y; a.z += b.z; a.w += b.w;
        *(float4*)(outp + i) = a;
        return;
    }
    const int nb = blockIdx.x;                     // 0..2047
    const int lane = threadIdx.x & 63, w = threadIdx.x >> 6;
#pragma unroll 1
    for (int i = 0; i < 8; ++i) {
        const int row = nb * 32 + w * 8 + i;
        const float iv = invg[row];
        float* rowf = attn + (size_t)row * L_;
        unsigned* rw = (unsigned*)rowf;
        unsigned u[17];
#pragma unroll
        for (int it = 0; it < 16; ++it) u[it] = rw[lane + it * 64];
        if (lane < 20) u[16] = rw[lane + 1024];
        asm volatile("s_waitcnt vmcnt(0)" ::: "memory");   // all reads in regs
#pragma unroll
        for (int it = 0; it < 16; ++it) {
            unsigned uu = u[it];
            float2 v;
            v.x = __builtin_bit_cast(float, uu << 16) * iv;
            v.y = __builtin_bit_cast(float, uu & 0xFFFF0000u) * iv;
            *(float2*)(rowf + 2 * (lane + it * 64)) = v;
        }
        if (lane < 20) {
            unsigned uu = u[16];
            float2 v;
            v.x = __builtin_bit_cast(float, uu << 16) * iv;
            v.y = __builtin_bit_cast(float, uu & 0xFFFF0000u) * iv;
            *(float2*)(rowf + 2 * (lane + 1024)) = v;
        }
    }
}

// ---------------------------------------------------------------------------
extern "C" void kernel_launch(void* const* d_in, const int* in_sizes, int n_in,
                              void* d_out, int out_size, void* d_ws, size_t ws_size,
                              hipStream_t stream)
{
    const float* v_in = (const float*)d_in[0];
    const float* k_in = (const float*)d_in[1];
    const float* q_in = (const float*)d_in[2];
    const float* mask = (const float*)d_in[3];
    const float* Wq = (const float*)d_in[4];  const float* bq = (const float*)d_in[5];
    const float* Wk = (const float*)d_in[6];  const float* bk = (const float*)d_in[7];
    const float* Wv = (const float*)d_in[8];  const float* bv = (const float*)d_in[9];
    const float* kmem = (const float*)d_in[10];
    const float* vmem = (const float*)d_in[11];
    const float* Wkm = (const float*)d_in[12]; const float* bkm = (const float*)d_in[13];
    const float* Wvm = (const float*)d_in[14]; const float* bvm = (const float*)d_in[15];
    const float* Wo = (const float*)d_in[16];  const float* bo = (const float*)d_in[17];

    // ---- workspace (86 MB) ----
    char* wsb = (char*)d_ws;
    short* WT  = (short*)(wsb);                       // 6 * 4 MB = 25,165,824 B
    short* Qhb = (short*)(wsb + 25165824);            // 8,388,608 B
    short* Qlb = (short*)(wsb + 33554432);            // 8,388,608 B
    short* Khb = (short*)(wsb + 41943040);            // 8,650,752 B
    short* Klb = (short*)(wsb + 50593792);            // 8,650,752 B
    short* Vhb = (short*)(wsb + 59244544);            // 8,650,752 B
    short* Chb = (short*)(wsb + 67895296);            // 8,388,608 B
    short* Clb = (short*)(wsb + 76283904);            // 8,388,608 B
    float* invb = (float*)(wsb + 84672512);           // 262,144 B
    unsigned* mp = (unsigned*)(wsb + 84934656);       // 1,114,112 B
    if (ws_size < 86048768) return;
    // split-K partial buffers reuse dead Q / K hi+lo regions after attn4
    float* Po0 = (float*)(wsb + 25165824);            // 16,777,216 B (Qhb+Qlb)
    float* Po1 = (float*)(wsb + 41943040);            // 16,777,216 B (Khb+Klb)

    float* outp = (float*)d_out;                      // [B,S,D]
    float* attnp = outp + (size_t)B_ * S_ * 1024;     // [B,H,S,L]

    dim3 blk(256);

    wsplit6_kernel<<<dim3(16, 16, 6), blk, 0, stream>>>(Wq, Wk, Wv, Wkm, Wvm, Wo, WT);

    // mask pack (z=0) + projections (z=1..3) + memory GEMMs (z=4..7)
    qkv_gemm<<<dim3(8, 32, 8), blk, 0, stream>>>(
        q_in, k_in, v_in, kmem, vmem, WT, bq, bk, bv, bkm, bvm,
        Qhb, Qlb, Khb, Klb, Vhb, mask, mp);

    // fused attention: 1024 blocks x 4 waves, single-buffered LDS, 4 blk/CU
    attn4_kernel<<<dim3(1024), blk, 0, stream>>>(
        Qhb, Qlb, Khb, Klb, Vhb, mp, attnp, invb, Chb, Clb);

    // out projection (split-K=2 into dead Q/K buffers)
    out_gemm<<<dim3(8, 32, 2), blk, 0, stream>>>(Chb, Clb, WT, bo, Po0, Po1);

    // fused BW tail: expand+normalize attn + split-K partial sum (LDS-free)
    norm_add<<<dim3(2048 + 4096), blk, 0, stream>>>(attnp, invb, Po0, Po1, outp);
}

// Round 20
// 569.752 us; speedup vs baseline: 1.0570x; 1.0570x over previous
//
#include <hip/hip_runtime.h>
#include <hip/hip_bf16.h>

typedef __attribute__((ext_vector_type(8))) short short8v;
typedef __attribute__((ext_vector_type(4))) short short4v;
typedef __attribute__((ext_vector_type(4))) float f32x4;

constexpr int B_ = 2, S_ = 2048, H_ = 16, MM_ = 40;
constexpr int L_ = S_ + MM_;    // 2088
constexpr int LP_ = 2112;       // 33 * 64 padded kv length
constexpr int NT_ = 33;         // l tiles of 64
constexpr float QSCALE = 0.18033688011112042f;   // 0.125/ln2 folded into Q proj

struct S2 { short hi, lo; };
__device__ __forceinline__ S2 split2(float f) {
    unsigned u = __builtin_bit_cast(unsigned, f);
    short hi = (short)(u >> 16);
    float fh = __builtin_bit_cast(float, u & 0xFFFF0000u);
    float fl = f - fh;                       // exact
    short lo = (short)(__builtin_bit_cast(unsigned, fl) >> 16);
    return {hi, lo};
}
__device__ __forceinline__ short f2bh(float f) {
    unsigned u = __builtin_bit_cast(unsigned, f);
    u = (u + 0x7FFFu + ((u >> 16) & 1u)) >> 16;
    return (short)u;
}
__device__ __forceinline__ f32x4 mfma16(short8v a, short8v b, f32x4 c) {
    return __builtin_amdgcn_mfma_f32_16x16x32_bf16(a, b, c, 0, 0, 0);
}
__device__ __forceinline__ unsigned cvt_pk_bf16(float a, float b) {
    unsigned r;
    asm("v_cvt_pk_bf16_f32 %0, %1, %2" : "=v"(r) : "v"(a), "v"(b));
    return r;
}

// ---------------------------------------------------------------------------
// Weight split+transpose (batched z=6): W[k][n] -> WTh/WTl[n][k] bf16 hi/lo.
// ---------------------------------------------------------------------------
__global__ __launch_bounds__(256) void wsplit6_kernel(
    const float* __restrict__ W0, const float* __restrict__ W1,
    const float* __restrict__ W2, const float* __restrict__ W3,
    const float* __restrict__ W4, const float* __restrict__ W5,
    short* __restrict__ WT)
{
    const float* Ws[6] = {W0, W1, W2, W3, W4, W5};
    const float* W = Ws[blockIdx.z];
    short* WTh = WT + (size_t)blockIdx.z * 2097152;
    short* WTl = WTh + 1048576;
    __shared__ float T[64][68];
    const int t = threadIdx.x;
    const int k0 = blockIdx.x * 64, n0 = blockIdx.y * 64;
    {
        int r = t >> 2, c = (t & 3) * 16;
        const float* src = W + (size_t)(k0 + r) * 1024 + n0 + c;
        *(float4*)&T[r][c + 0]  = *(const float4*)(src + 0);
        *(float4*)&T[r][c + 4]  = *(const float4*)(src + 4);
        *(float4*)&T[r][c + 8]  = *(const float4*)(src + 8);
        *(float4*)&T[r][c + 12] = *(const float4*)(src + 12);
    }
    __syncthreads();
    {
        int n = t >> 2, ks = (t & 3) * 16;
        short8v h0, h1, l0, l1;
#pragma unroll
        for (int j = 0; j < 8; ++j) {
            S2 a = split2(T[ks + j][n]);     h0[j] = a.hi; l0[j] = a.lo;
            S2 b = split2(T[ks + 8 + j][n]); h1[j] = b.hi; l1[j] = b.lo;
        }
        size_t dst = (size_t)(n0 + n) * 1024 + k0 + ks;
        *(short8v*)(WTh + dst) = h0;  *(short8v*)(WTh + dst + 8) = h1;
        *(short8v*)(WTl + dst) = l0;  *(short8v*)(WTl + dst + 8) = l1;
    }
}

// ---------------------------------------------------------------------------
// GEMM device core: 128x128 tile, BK=32, split-bf16 3-term MFMA.
// ---------------------------------------------------------------------------
template<int ASRC>
__device__ __forceinline__ void gemm_core(
    const float* __restrict__ Af, const short* __restrict__ Ahg,
    const short* __restrict__ Alg, const short* __restrict__ WTh,
    const short* __restrict__ WTl, const float* __restrict__ bias,
    float bscale, float scale,
    short* __restrict__ Oh, short* __restrict__ Ol, float* __restrict__ Of,
    int M, int RPB, int TD, int loff, int omode, int bx, int by,
    int kbeg, int kend)
{
    __shared__ short Ah[128][40];
    __shared__ short Al[128][40];
    __shared__ short Bh[128][40];
    __shared__ short Bl[128][40];
    const int tid = threadIdx.x;
    const int lane = tid & 63, wid = tid >> 6;
    const int wr = wid >> 1, wc = wid & 1;
    const int row0 = by * 128, col0 = bx * 128;
    const int sr = tid >> 1, sc = (tid & 1) << 4;

    f32x4 acc[4][4] = {};

    for (int k0 = kbeg; k0 < kend; k0 += 32) {
        if (ASRC == 0) {
            float f[16];
            int gr = row0 + sr;
            if (gr < M) {
                const float* ap = Af + (size_t)gr * 1024 + k0 + sc;
                float4 a0 = *(const float4*)(ap + 0);
                float4 a1 = *(const float4*)(ap + 4);
                float4 a2 = *(const float4*)(ap + 8);
                float4 a3 = *(const float4*)(ap + 12);
                f[0]=a0.x; f[1]=a0.y; f[2]=a0.z; f[3]=a0.w;
                f[4]=a1.x; f[5]=a1.y; f[6]=a1.z; f[7]=a1.w;
                f[8]=a2.x; f[9]=a2.y; f[10]=a2.z; f[11]=a2.w;
                f[12]=a3.x; f[13]=a3.y; f[14]=a3.z; f[15]=a3.w;
            } else {
#pragma unroll
                for (int j = 0; j < 16; ++j) f[j] = 0.f;
            }
            short8v h0, h1, l0, l1;
#pragma unroll
            for (int j = 0; j < 8; ++j) {
                S2 s = split2(f[j]); h0[j] = s.hi; l0[j] = s.lo;
            }
#pragma unroll
            for (int j = 0; j < 8; ++j) {
                S2 s = split2(f[8 + j]); h1[j] = s.hi; l1[j] = s.lo;
            }
            *(short8v*)&Ah[sr][sc] = h0; *(short8v*)&Ah[sr][sc + 8] = h1;
            *(short8v*)&Al[sr][sc] = l0; *(short8v*)&Al[sr][sc + 8] = l1;
        } else {
            const short* ah = Ahg + (size_t)(row0 + sr) * 1024 + k0 + sc;
            const short* al = Alg + (size_t)(row0 + sr) * 1024 + k0 + sc;
            *(short8v*)&Ah[sr][sc]     = *(const short8v*)ah;
            *(short8v*)&Ah[sr][sc + 8] = *(const short8v*)(ah + 8);
            *(short8v*)&Al[sr][sc]     = *(const short8v*)al;
            *(short8v*)&Al[sr][sc + 8] = *(const short8v*)(al + 8);
        }
        {
            const short* bh = WTh + (size_t)(col0 + sr) * 1024 + k0 + sc;
            const short* bl = WTl + (size_t)(col0 + sr) * 1024 + k0 + sc;
            *(short8v*)&Bh[sr][sc]     = *(const short8v*)bh;
            *(short8v*)&Bh[sr][sc + 8] = *(const short8v*)(bh + 8);
            *(short8v*)&Bl[sr][sc]     = *(const short8v*)bl;
            *(short8v*)&Bl[sr][sc + 8] = *(const short8v*)(bl + 8);
        }
        __syncthreads();
        const int kof = (lane >> 4) << 3;
        const int ar = lane & 15;
        short8v afh[4], afl[4], bfh[4], bfl[4];
#pragma unroll
        for (int i = 0; i < 4; ++i) {
            afh[i] = *(const short8v*)&Ah[wr * 64 + i * 16 + ar][kof];
            afl[i] = *(const short8v*)&Al[wr * 64 + i * 16 + ar][kof];
            bfh[i] = *(const short8v*)&Bh[wc * 64 + i * 16 + ar][kof];
            bfl[i] = *(const short8v*)&Bl[wc * 64 + i * 16 + ar][kof];
        }
#pragma unroll
        for (int i = 0; i < 4; ++i)
#pragma unroll
            for (int j = 0; j < 4; ++j) {
                acc[i][j] = mfma16(afh[i], bfh[j], acc[i][j]);
                acc[i][j] = mfma16(afh[i], bfl[j], acc[i][j]);
                acc[i][j] = mfma16(afl[i], bfh[j], acc[i][j]);
            }
        __syncthreads();
    }

#pragma unroll
    for (int i = 0; i < 4; ++i) {
#pragma unroll
        for (int j = 0; j < 4; ++j) {
            int colb = col0 + wc * 64 + j * 16 + (lane & 15);
            float bv = bias[colb] * bscale;
            int rowb = row0 + wr * 64 + i * 16 + ((lane >> 4) << 2);
            if (omode == 2) {
                if (rowb < M) {
                    int bb = rowb / RPB, tt = rowb % RPB;
                    int hh = colb >> 6, dh = colb & 63;
                    short4v hs;
#pragma unroll
                    for (int r = 0; r < 4; ++r)
                        hs[r] = f2bh((acc[i][j][r] + bv) * scale);
                    size_t dst = ((size_t)(bb * H_ + hh) * 64 + dh) * LP_ + loff + tt;
                    *(short4v*)(Oh + dst) = hs;
                }
            } else {
#pragma unroll
                for (int r = 0; r < 4; ++r) {
                    int row = rowb + r;
                    if (row < M) {
                        float o = (acc[i][j][r] + bv) * scale;
                        int bb = row / RPB, tt = row % RPB;
                        if (omode == 0) {
                            Of[((size_t)bb * TD + loff + tt) * 1024 + colb] = o;
                        } else {
                            int hh = colb >> 6, dh = colb & 63;
                            size_t dst = ((size_t)(bb * H_ + hh) * TD + loff + tt) * 64 + dh;
                            S2 s = split2(o);
                            Oh[dst] = s.hi; Ol[dst] = s.lo;
                        }
                    }
                }
            }
        }
    }
}

// ---------------------------------------------------------------------------
// Mega projection kernel: z=0 = mask pack + V pad clear; z in {1,2,3} =
// Q/K/V big GEMMs; z in {4..7} = memory K/V GEMMs (by==0 only).
// ---------------------------------------------------------------------------
__global__ __launch_bounds__(256) void qkv_gemm(
    const float* __restrict__ q_in, const float* __restrict__ k_in,
    const float* __restrict__ v_in, const float* __restrict__ kmem,
    const float* __restrict__ vmem, const short* __restrict__ WT,
    const float* __restrict__ bq, const float* __restrict__ bk,
    const float* __restrict__ bv, const float* __restrict__ bkm,
    const float* __restrict__ bvm,
    short* __restrict__ Qh, short* __restrict__ Ql,
    short* __restrict__ Kh, short* __restrict__ Kl, short* __restrict__ Vh,
    const float* __restrict__ mask, unsigned* __restrict__ mp)
{
    const int z = blockIdx.z;
    if (z == 0) {
        const int blk = blockIdx.y * 8 + blockIdx.x;      // 0..255
        for (int rr = 0; rr < 16; ++rr) {
            const int row = blk * 16 + rr;
            const float* mr = mask + (size_t)row * L_;
            unsigned* orow = mp + (size_t)row * 68;
            for (int wd = threadIdx.x; wd < 66; wd += 256) {
                int l0 = wd * 32;
                unsigned bits = 0u;
                int lim = (wd < 65) ? 32 : 8;
                for (int j = 0; j < lim; j += 4) {
                    float4 m4 = *(const float4*)(mr + l0 + j);
                    bits |= ((unsigned)(m4.x != 0.f)) << (j + 0);
                    bits |= ((unsigned)(m4.y != 0.f)) << (j + 1);
                    bits |= ((unsigned)(m4.z != 0.f)) << (j + 2);
                    bits |= ((unsigned)(m4.w != 0.f)) << (j + 3);
                }
                if (wd == 65) bits |= 0xFFFFFF00u;
                orow[wd] = bits;
            }
        }
        for (int k = threadIdx.x; k < 192; k += 256) {
            int g = blk * 192 + k;
            int rd = g / 24, l = L_ + g % 24;
            Vh[(size_t)rd * LP_ + l] = 0;
        }
        return;
    }
    if (z >= 4) {
        if (blockIdx.y != 0) return;
        const int which = (z - 4) >> 1, b = (z - 4) & 1;   // which: 0=K, 1=V
        const float* A = which ? vmem : kmem;
        const short* WTh = WT + (size_t)(3 + which) * 2097152;
        const short* WTl = WTh + 1048576;
        const float* bias = which ? bvm : bkm;
        short* Oh = which ? (Vh + (size_t)b * H_ * 64 * LP_)
                          : (Kh + (size_t)b * H_ * LP_ * 64);
        short* Ol = which ? nullptr : (Kl + (size_t)b * H_ * LP_ * 64);
        gemm_core<0>(A, nullptr, nullptr, WTh, WTl, bias, 1.0f, 1.0f,
                     Oh, Ol, nullptr, 40, 40, LP_, S_, which ? 2 : 1,
                     blockIdx.x, 0, 0, 1024);
        return;
    }
    const int g = z - 1;                           // 0=Q 1=K 2=V
    const float* A = (g == 0) ? q_in : (g == 1) ? k_in : v_in;
    const short* WTh = WT + (size_t)g * 2097152;
    const short* WTl = WTh + 1048576;
    const float* bias = (g == 0) ? bq : (g == 1) ? bk : bv;
    float scale = (g == 0) ? QSCALE : 1.0f;
    short* Oh = (g == 0) ? Qh : (g == 1) ? Kh : Vh;
    short* Ol = (g == 0) ? Ql : Kl;
    int omode = (g == 2) ? 2 : 1;
    int TD = (g == 0) ? S_ : LP_;
    gemm_core<0>(A, nullptr, nullptr, WTh, WTl, bias, 1.0f, scale,
                 Oh, Ol, nullptr, 4096, 2048, TD, 0, omode,
                 blockIdx.x, blockIdx.y, 0, 1024);
}

// ---------------------------------------------------------------------------
// Out projection, split-K=2: z selects K half; writes fp32 partials.
// ---------------------------------------------------------------------------
__global__ __launch_bounds__(256) void out_gemm(
    const short* __restrict__ Ch, const short* __restrict__ Cl,
    const short* __restrict__ WT, const float* __restrict__ bo,
    float* __restrict__ Po0, float* __restrict__ Po1)
{
    const int z = blockIdx.z;
    const short* WTh = WT + (size_t)5 * 2097152;
    gemm_core<1>(nullptr, Ch, Cl, WTh, WTh + 1048576, bo,
                 z == 0 ? 1.0f : 0.0f, 1.0f,
                 nullptr, nullptr, z == 0 ? Po0 : Po1, 4096, 2048, S_, 0, 0,
                 blockIdx.x, blockIdx.y, z * 512, z * 512 + 512);
}

// ---------------------------------------------------------------------------
// Sum the two split-K partials into d_out.
// ---------------------------------------------------------------------------
__global__ __launch_bounds__(256) void add_out(
    const float* __restrict__ Po0, const float* __restrict__ Po1,
    float* __restrict__ outp)
{
    int i = (blockIdx.x * 256 + threadIdx.x) * 4;   // 4,194,304 floats
    float4 a = *(const float4*)(Po0 + i);
    float4 b = *(const float4*)(Po1 + i);
    a.x += b.x; a.y += b.y; a.z += b.z; a.w += b.w;
    *(float4*)(outp + i) = a;
}

// ---------------------------------------------------------------------------
// Fused attention v12: SINGLE-buffered K and V -> 32.7 KB LDS -> 4 blocks/CU
// (16 waves/CU). 1024 blocks x 4 waves, 64 q-rows/block.
// Schedule: compute(t) -> barrier -> stage(t+1) -> barrier; the stage
// latency between barriers is hidden by the other 3 resident blocks.
// ---------------------------------------------------------------------------
__global__ __launch_bounds__(256) void attn4_kernel(
    const short* __restrict__ Qh, const short* __restrict__ Ql,
    const short* __restrict__ Kh, const short* __restrict__ Kl,
    const short* __restrict__ Vh, const unsigned* __restrict__ mp,
    float* __restrict__ attn, float* __restrict__ invg,
    short* __restrict__ Ch, short* __restrict__ Cl)
{
    __shared__ short KhB[64][64];      // 8 KB
    __shared__ short KlB[64][64];      // 8 KB
    __shared__ short VB[64][64];       // 8 KB
    __shared__ short Ph[4][16][68];    // 8.5 KB

    const int id = blockIdx.x;
    const int wg = (id & 7) * 128 + (id >> 3);     // XCD swizzle (1024 = 8*128)
    const int bh = wg >> 5, qb = wg & 31;
    const int b = bh >> 4, h = bh & 15;
    const int lane = threadIdx.x & 63, w = threadIdx.x >> 6;
    const int lq = lane & 15, hi = lane >> 4;
    const int sw = lq & 7;
    const int q0 = qb * 64 + w * 16;
    const int q = q0 + lq;

    const char* kh_g = (const char*)(Kh + (size_t)bh * LP_ * 64);
    const char* kl_g = (const char*)(Kl + (size_t)bh * LP_ * 64);
    const char* v_g  = (const char*)(Vh + (size_t)bh * 64 * LP_);

    // each of the 4 waves stages 2KB of each 8KB tile
    auto stage_k = [&](int tt) {
#pragma unroll
        for (int i = 0; i < 2; ++i) {
            int o = w * 2048 + i * 1024 + lane * 16;   // linear LDS byte offset
            int r = o >> 7, c = (o >> 4) & 7;
            int cs = c ^ (r & 7);                      // inverse-swizzled source
            const char* sh = kh_g + (size_t)tt * 8192 + r * 128 + cs * 16;
            const char* sl = kl_g + (size_t)tt * 8192 + r * 128 + cs * 16;
            __builtin_amdgcn_global_load_lds((const void*)sh,
                (void*)((char*)&KhB[0][0] + w * 2048 + i * 1024), 16, 0, 0);
            __builtin_amdgcn_global_load_lds((const void*)sl,
                (void*)((char*)&KlB[0][0] + w * 2048 + i * 1024), 16, 0, 0);
        }
    };
    auto stage_v = [&](int tt) {
#pragma unroll
        for (int i = 0; i < 2; ++i) {
            int o = w * 2048 + i * 1024 + lane * 16;
            int dh = o >> 7, c = (o >> 4) & 7;
            int cs = c ^ (dh & 7);
            const char* src = v_g + (size_t)dh * (LP_ * 2) + (size_t)tt * 128 + cs * 16;
            __builtin_amdgcn_global_load_lds((const void*)src,
                (void*)((char*)&VB[0][0] + w * 2048 + i * 1024), 16, 0, 0);
        }
    };

    const size_t qbase = ((size_t)bh * S_ + q) * 64 + hi * 8;
    const short8v qh0 = *(const short8v*)(Qh + qbase);
    const short8v qh1 = *(const short8v*)(Qh + qbase + 32);
    const short8v ql0 = *(const short8v*)(Ql + qbase);
    const short8v ql1 = *(const short8v*)(Ql + qbase + 32);
    const unsigned* mrow = mp + ((size_t)b * S_ + q) * 68;

    const int dr = lane >> 2, dc = lane & 3;
    short* dbase = (short*)(attn + ((size_t)bh * S_ + q0 + dr) * L_);

    float sm = 0.f;
    f32x4 pv[4] = {};

    stage_k(0);
    stage_v(0);
    __syncthreads();

    for (int t = 0; t < NT_; ++t) {
        const unsigned w0 = mrow[2 * t], w1 = mrow[2 * t + 1];
        const short8v* kp = (const short8v*)&KhB[0][0];
        const short8v* lp = (const short8v*)&KlB[0][0];
#pragma unroll
        for (int ls = 0; ls < 4; ++ls) {
            const int r = ls * 16 + lq;
            const short8v kh0 = kp[r * 8 + (hi ^ sw)];
            const short8v kh1 = kp[r * 8 + ((hi + 4) ^ sw)];
            const short8v kl0 = lp[r * 8 + (hi ^ sw)];
            const short8v kl1 = lp[r * 8 + ((hi + 4) ^ sw)];
            __builtin_amdgcn_s_setprio(1);
            f32x4 acc = {0.f, 0.f, 0.f, 0.f};
            acc = mfma16(kh0, qh0, acc); acc = mfma16(kh1, qh1, acc);
            acc = mfma16(kh0, ql0, acc); acc = mfma16(kh1, ql1, acc);
            acc = mfma16(kl0, qh0, acc); acc = mfma16(kl1, qh1, acc);
            __builtin_amdgcn_s_setprio(0);
            const unsigned wb = (ls & 2) ? w1 : w0;
            const int sh = (ls & 1) * 16 + hi * 4;
            float pr[4];
#pragma unroll
            for (int r2 = 0; r2 < 4; ++r2) {
                float e = __builtin_exp2f(acc[r2]);
                pr[r2] = ((wb >> (sh + r2)) & 1u) ? 0.f : e;
            }
            sm += (pr[0] + pr[1]) + (pr[2] + pr[3]);
            *(uint2*)&Ph[w][lq][ls * 16 + hi * 4] =
                uint2{cvt_pk_bf16(pr[0], pr[1]), cvt_pk_bf16(pr[2], pr[3])};
        }
        {   // dense packed-bf16 p~ store (from Ph)
            short8v v0 = *(const short8v*)&Ph[w][dr][dc * 8];
            short8v v1 = *(const short8v*)&Ph[w][dr][32 + dc * 8];
            short* dst = dbase + t * 64 + dc * 8;
            if (t < NT_ - 1) { *(short8v*)dst = v0; *(short8v*)(dst + 32) = v1; }
            else { *(short8v*)dst = v0; if (dc == 0) *(short8v*)(dst + 32) = v1; }
        }
        {   // PV
            const short8v pa0 = *(const short8v*)&Ph[w][lq][hi * 8];
            const short8v pa1 = *(const short8v*)&Ph[w][lq][32 + hi * 8];
            const short8v* vp = (const short8v*)&VB[0][0];
            __builtin_amdgcn_s_setprio(1);
#pragma unroll
            for (int j = 0; j < 4; ++j)
                pv[j] = mfma16(pa0, vp[(j * 16 + lq) * 8 + (hi ^ sw)], pv[j]);
#pragma unroll
            for (int j = 0; j < 4; ++j)
                pv[j] = mfma16(pa1, vp[(j * 16 + lq) * 8 + ((hi + 4) ^ sw)], pv[j]);
            __builtin_amdgcn_s_setprio(0);
        }
        if (t < NT_ - 1) {
            __syncthreads();            // all reads of the buffers done
            stage_k(t + 1);
            stage_v(t + 1);
            __syncthreads();            // staged data visible
        }
    }

    // row sums (lane l holds sum of row q0 + (l&15))
    sm += __shfl_xor(sm, 16);
    sm += __shfl_xor(sm, 32);
    if (lane < 16)
        invg[(size_t)bh * S_ + q0 + lane] = sm > 0.f ? 1.0f / sm : 0.f;

    // ctx write (normalized, split bf16)
#pragma unroll
    for (int r = 0; r < 4; ++r) {
        float sv = __shfl(sm, hi * 4 + r);
        float iv = sv > 0.f ? 1.0f / sv : 0.f;
#pragma unroll
        for (int j = 0; j < 4; ++j) {
            size_t dst = ((size_t)b * S_ + q0 + hi * 4 + r) * 1024 + h * 64 + j * 16 + lq;
            S2 sp = split2(pv[j][r] * iv);
            Ch[dst] = sp.hi; Cl[dst] = sp.lo;
        }
    }
}

// ---------------------------------------------------------------------------
// Standalone expand+normalize: LDS-free, reg-staged rows, 2048 blocks x 4
// waves x 8 rows. High occupancy (no LDS, low VGPR).
// ---------------------------------------------------------------------------
__global__ __launch_bounds__(256) void norm_attn(
    float* __restrict__ attn, const float* __restrict__ invg)
{
    const int nb = blockIdx.x;                     // 0..2047
    const int lane = threadIdx.x & 63, w = threadIdx.x >> 6;
#pragma unroll 1
    for (int i = 0; i < 8; ++i) {
        const int row = nb * 32 + w * 8 + i;
        const float iv = invg[row];
        float* rowf = attn + (size_t)row * L_;
        unsigned* rw = (unsigned*)rowf;
        unsigned u[17];
#pragma unroll
        for (int it = 0; it < 16; ++it) u[it] = rw[lane + it * 64];
        if (lane < 20) u[16] = rw[lane + 1024];
        asm volatile("s_waitcnt vmcnt(0)" ::: "memory");   // all reads in regs
#pragma unroll
        for (int it = 0; it < 16; ++it) {
            unsigned uu = u[it];
            float2 v;
            v.x = __builtin_bit_cast(float, uu << 16) * iv;
            v.y = __builtin_bit_cast(float, uu & 0xFFFF0000u) * iv;
            *(float2*)(rowf + 2 * (lane + it * 64)) = v;
        }
        if (lane < 20) {
            unsigned uu = u[16];
            float2 v;
            v.x = __builtin_bit_cast(float, uu << 16) * iv;
            v.y = __builtin_bit_cast(float, uu & 0xFFFF0000u) * iv;
            *(float2*)(rowf + 2 * (lane + 1024)) = v;
        }
    }
}

// ---------------------------------------------------------------------------
extern "C" void kernel_launch(void* const* d_in, const int* in_sizes, int n_in,
                              void* d_out, int out_size, void* d_ws, size_t ws_size,
                              hipStream_t stream)
{
    const float* v_in = (const float*)d_in[0];
    const float* k_in = (const float*)d_in[1];
    const float* q_in = (const float*)d_in[2];
    const float* mask = (const float*)d_in[3];
    const float* Wq = (const float*)d_in[4];  const float* bq = (const float*)d_in[5];
    const float* Wk = (const float*)d_in[6];  const float* bk = (const float*)d_in[7];
    const float* Wv = (const float*)d_in[8];  const float* bv = (const float*)d_in[9];
    const float* kmem = (const float*)d_in[10];
    const float* vmem = (const float*)d_in[11];
    const float* Wkm = (const float*)d_in[12]; const float* bkm = (const float*)d_in[13];
    const float* Wvm = (const float*)d_in[14]; const float* bvm = (const float*)d_in[15];
    const float* Wo = (const float*)d_in[16];  const float* bo = (const float*)d_in[17];

    // ---- workspace (86 MB) ----
    char* wsb = (char*)d_ws;
    short* WT  = (short*)(wsb);                       // 6 * 4 MB = 25,165,824 B
    short* Qhb = (short*)(wsb + 25165824);            // 8,388,608 B
    short* Qlb = (short*)(wsb + 33554432);            // 8,388,608 B
    short* Khb = (short*)(wsb + 41943040);            // 8,650,752 B
    short* Klb = (short*)(wsb + 50593792);            // 8,650,752 B
    short* Vhb = (short*)(wsb + 59244544);            // 8,650,752 B
    short* Chb = (short*)(wsb + 67895296);            // 8,388,608 B
    short* Clb = (short*)(wsb + 76283904);            // 8,388,608 B
    float* invb = (float*)(wsb + 84672512);           // 262,144 B
    unsigned* mp = (unsigned*)(wsb + 84934656);       // 1,114,112 B
    if (ws_size < 86048768) return;
    // split-K partial buffers reuse dead Q / K hi+lo regions after attn4
    float* Po0 = (float*)(wsb + 25165824);            // 16,777,216 B (Qhb+Qlb)
    float* Po1 = (float*)(wsb + 41943040);            // 16,777,216 B (Khb+Klb)

    float* outp = (float*)d_out;                      // [B,S,D]
    float* attnp = outp + (size_t)B_ * S_ * 1024;     // [B,H,S,L]

    dim3 blk(256);

    wsplit6_kernel<<<dim3(16, 16, 6), blk, 0, stream>>>(Wq, Wk, Wv, Wkm, Wvm, Wo, WT);

    // mask pack (z=0) + projections (z=1..3) + memory GEMMs (z=4..7)
    qkv_gemm<<<dim3(8, 32, 8), blk, 0, stream>>>(
        q_in, k_in, v_in, kmem, vmem, WT, bq, bk, bv, bkm, bvm,
        Qhb, Qlb, Khb, Klb, Vhb, mask, mp);

    // fused attention: 1024 blocks x 4 waves, single-buffered LDS, 4 blk/CU
    attn4_kernel<<<dim3(1024), blk, 0, stream>>>(
        Qhb, Qlb, Khb, Klb, Vhb, mp, attnp, invb, Chb, Clb);

    // out projection (split-K=2 into dead Q/K buffers) + partial sum
    out_gemm<<<dim3(8, 32, 2), blk, 0, stream>>>(Chb, Clb, WT, bo, Po0, Po1);
    add_out<<<dim3(4096), blk, 0, stream>>>(Po0, Po1, outp);

    // standalone expand+normalize (LDS-free, high occupancy)
    norm_attn<<<dim3(2048), blk, 0, stream>>>(attnp, invb);
}